// Round 1
// baseline (213.814 us; speedup 1.0000x reference)
//
#include <hip/hip_runtime.h>
#include <hip/hip_bf16.h>

#define CIN 32
#define OCH 64
#define HH 256
#define WW 256
#define KTOT 288   // 32*9

typedef __bf16 bf16x8 __attribute__((ext_vector_type(8)));
typedef __bf16 bf16x2 __attribute__((ext_vector_type(2)));
typedef float  f32x4  __attribute__((ext_vector_type(4)));

// Re-layout weight: wt[o][tap*32 + c] = bf16(weight[o][c*9 + tap])
__global__ void wprep_kernel(const float* __restrict__ w, __bf16* __restrict__ wt) {
    int i = blockIdx.x * 256 + threadIdx.x;   // 0 .. 64*288-1
    if (i < OCH * KTOT) {
        int o  = i / KTOT;
        int kp = i - o * KTOT;
        int tap = kp >> 5;       // 0..8
        int c   = kp & 31;       // 0..31
        wt[i] = (__bf16)w[o * KTOT + c * 9 + tap];
    }
}

__global__ __launch_bounds__(256) void conv_mfma_kernel(
        const float* __restrict__ x, const __bf16* __restrict__ wt,
        const float* __restrict__ bias, float* __restrict__ out) {
    const int h = blockIdx.x;
    const int b = blockIdx.y;
    const int tid = threadIdx.x;

    // LDS: 3 rows x (256+2 pad) w x 32 channels, bf16. 49,536 B.
    __shared__ __bf16 xs[3][258][CIN];

    // ---------------- staging: global f32 -> LDS bf16 ----------------
    {
        const int lane_w = tid & 15;   // 16 w-pair slots
        const int cp     = tid >> 4;   // 16 channel-pairs
        const float* xb = x + (size_t)b * CIN * HH * WW;
#pragma unroll
        for (int r = 0; r < 3; ++r) {
            const int row = h - 1 + r;
            const bool rok = (row >= 0) && (row < HH);
#pragma unroll
            for (int j = 0; j < 8; ++j) {
                const int wg0 = j * 32 + lane_w * 2;   // even, 0..254
                float2 v0 = make_float2(0.f, 0.f);
                float2 v1 = make_float2(0.f, 0.f);
                if (rok) {
                    const float* p0 = xb + ((size_t)(2 * cp) * HH + row) * WW + wg0;
                    v0 = *(const float2*)p0;             // channel 2cp,  w = wg0..wg0+1
                    v1 = *(const float2*)(p0 + HH * WW); // channel 2cp+1
                }
                bf16x2 pk0 = { (__bf16)v0.x, (__bf16)v1.x };  // w = wg0   -> wp = wg0+1
                bf16x2 pk1 = { (__bf16)v0.y, (__bf16)v1.y };  // w = wg0+1 -> wp = wg0+2
                *(bf16x2*)&xs[r][wg0 + 1][2 * cp] = pk0;
                *(bf16x2*)&xs[r][wg0 + 2][2 * cp] = pk1;
            }
        }
        if (tid < 48) {   // zero the w-pad columns wp=0 and wp=257
            int r = tid / 16, cc = (tid % 16) * 2;
            bf16x2 z = { (__bf16)0.f, (__bf16)0.f };
            *(bf16x2*)&xs[r][0][cc]   = z;
            *(bf16x2*)&xs[r][257][cc] = z;
        }
    }
    __syncthreads();

    // ---------------- compute: implicit GEMM, 16x16x32 bf16 MFMA ----------------
    const int l   = tid & 63;
    const int wid = tid >> 6;      // wave 0..3 -> output channels wid*16..+15
    const int lm  = l & 15;        // A-row(o) / B-col(w) / D-col
    const int lh  = l >> 4;        // 0..3 (K-split group)

    // A fragments: wt[o][t*32 + lh*8 .. +7], one per tap
    bf16x8 af[9];
    {
        const __bf16* wtp = wt + (size_t)(wid * 16 + lm) * KTOT + lh * 8;
#pragma unroll
        for (int t = 0; t < 9; ++t)
            af[t] = *(const bf16x8*)(wtp + t * 32);
    }
    float bv[4];
#pragma unroll
    for (int r = 0; r < 4; ++r) bv[r] = bias[wid * 16 + lh * 4 + r];

    f32x4 acc[16];
#pragma unroll
    for (int nt = 0; nt < 16; ++nt) acc[nt] = (f32x4){0.f, 0.f, 0.f, 0.f};

#pragma unroll
    for (int nt = 0; nt < 16; ++nt) {
#pragma unroll
        for (int t = 0; t < 9; ++t) {
            const int kh = t / 3, kw = t - kh * 3;
            bf16x8 bf = *(const bf16x8*)&xs[kh][nt * 16 + lm + kw][lh * 8];
            acc[nt] = __builtin_amdgcn_mfma_f32_16x16x32_bf16(af[t], bf, acc[nt], 0, 0, 0);
        }
    }

    // ---------------- epilogue: D col = l&15 (w), row = (l>>4)*4+reg (o) ----------------
    float* outb = out + ((size_t)b * OCH) * HH * WW + (size_t)h * WW;
#pragma unroll
    for (int nt = 0; nt < 16; ++nt) {
        const int w0 = nt * 16 + lm;
#pragma unroll
        for (int r = 0; r < 4; ++r) {
            const int o = wid * 16 + lh * 4 + r;
            outb[(size_t)o * HH * WW + w0] = acc[nt][r] + bv[r];
        }
    }
}

extern "C" void kernel_launch(void* const* d_in, const int* in_sizes, int n_in,
                              void* d_out, int out_size, void* d_ws, size_t ws_size,
                              hipStream_t stream) {
    const float* x    = (const float*)d_in[0];
    const float* w    = (const float*)d_in[1];
    const float* bias = (const float*)d_in[2];
    float* out = (float*)d_out;
    __bf16* wt = (__bf16*)d_ws;   // 64*288*2 = 36,864 B

    hipLaunchKernelGGL(wprep_kernel, dim3((OCH * KTOT + 255) / 256), dim3(256), 0, stream, w, wt);
    hipLaunchKernelGGL(conv_mfma_kernel, dim3(HH, 16), dim3(256), 0, stream, x, wt, bias, out);
}

// Round 2
// 137.915 us; speedup vs baseline: 1.5503x; 1.5503x over previous
//
#include <hip/hip_runtime.h>
#include <hip/hip_bf16.h>

#define CIN 32
#define OCH 64
#define HH 256
#define WW 256
#define KTOT 288   // 32*9

typedef __bf16 bf16x8 __attribute__((ext_vector_type(8)));
typedef __bf16 bf16x2 __attribute__((ext_vector_type(2)));
typedef float  f32x4  __attribute__((ext_vector_type(4)));

typedef __attribute__((address_space(3))) unsigned int lds_u32;
typedef const __attribute__((address_space(1))) unsigned int glb_u32;

__device__ inline void gload_lds16(const void* g, void* l) {
    __builtin_amdgcn_global_load_lds((glb_u32*)g, (lds_u32*)l, 16, 0, 0);
}

// ---------------------------------------------------------------------------
// Re-layout weight: wt[o][tap*32 + c] = bf16(weight[o][c*9 + tap])
__global__ void wprep_kernel(const float* __restrict__ w, __bf16* __restrict__ wt) {
    int i = blockIdx.x * 256 + threadIdx.x;   // 0 .. 64*288-1
    if (i < OCH * KTOT) {
        int o  = i / KTOT;
        int kp = i - o * KTOT;
        int tap = kp >> 5;
        int c   = kp & 31;
        wt[i] = (__bf16)w[o * KTOT + c * 9 + tap];
    }
}

// ---------------------------------------------------------------------------
// Transpose+convert: x[b][c][h][w] f32 -> xt[b][h][w-entry] bf16, where each
// 64B w-entry holds 4 16B chunks; chunk for channels slot*8..+7 is stored at
// position slot ^ ((w>>1)&3)  (bank-conflict-free swizzle, keyed on global w).
__global__ __launch_bounds__(256) void xprep_kernel(const float* __restrict__ x,
                                                    __bf16* __restrict__ xt) {
    const int h = blockIdx.x, b = blockIdx.y;
    const int tid = threadIdx.x;
    const int slot = tid >> 6, wl = tid & 63;

    __shared__ __bf16 ls[WW][CIN];   // 16 KiB, one output row, swizzled

    const float* xb = x + (size_t)b * CIN * HH * WW + (size_t)h * WW;
#pragma unroll
    for (int wh = 0; wh < 4; ++wh) {
        const int w = wh * 64 + wl;
        bf16x8 v;
#pragma unroll
        for (int j = 0; j < 8; ++j)
            v[j] = (__bf16)xb[(size_t)(slot * 8 + j) * HH * WW + w];
        const int sp = slot ^ ((w >> 1) & 3);
        *(bf16x8*)((char*)&ls[0][0] + w * 64 + sp * 16) = v;
    }
    __syncthreads();

    const char* lsb = (const char*)&ls[0][0];
    bf16x8* dst = (bf16x8*)(xt + ((size_t)b * HH + h) * WW * CIN);
#pragma unroll
    for (int q = 0; q < 4; ++q) {
        const int chunk = q * 256 + tid;
        dst[chunk] = *(const bf16x8*)(lsb + chunk * 16);
    }
}

// ---------------------------------------------------------------------------
// Conv: per (b,h) block. Stage 3 xt rows via linear global_load_lds (async),
// then implicit GEMM with swizzled conflict-free ds_read_b128 B-fragments.
__global__ __launch_bounds__(256) void conv_mfma_kernel(
        const __bf16* __restrict__ xt, const __bf16* __restrict__ wt,
        const float* __restrict__ bias, float* __restrict__ out) {
    // XCD-aware swizzle: 4096 blocks, 8 XCDs -> each XCD gets 512 consecutive
    // (b,h) ids so h-neighbor blocks (sharing 2 of 3 rows) share an L2.
    const int bid = blockIdx.x;
    const int nid = (bid & 7) * 512 + (bid >> 3);
    const int h = nid & (HH - 1);
    const int b = nid >> 8;
    const int tid = threadIdx.x;
    const int l = tid & 63, wid = tid >> 6;
    const int lm = l & 15, lh = l >> 4;

    // [3 rows][258 w-entries][32 ch] bf16 = 49,536 B. Row stride 16,512 B.
    // Position wp holds global w = wp-1; wp=0 and wp=257 are zero pads.
    __shared__ __bf16 xs[3][258][CIN];

    // zero the pad entries (64 B each, 6 total)
    if (tid < 24) {
        const int r = tid >> 3, k = tid & 7;
        const int wp = (k < 4) ? 0 : 257;
        *(f32x4*)((char*)&xs[r][0][0] + wp * 64 + (k & 3) * 16) = (f32x4){0, 0, 0, 0};
    }

    // async stage: 3 rows x 16 KiB, linear copy into wp=1..256
    const char* xtb = (const char*)(xt + (size_t)b * HH * WW * CIN);
#pragma unroll
    for (int r = 0; r < 3; ++r) {
        const int row = h - 1 + r;
        char* ldsrow = (char*)&xs[r][1][0];
        if (row >= 0 && row < HH) {
            const char* src = xtb + (size_t)row * (WW * CIN * 2);
#pragma unroll
            for (int i = 0; i < 4; ++i) {
                const int off = (wid * 4 + i) * 1024;
                gload_lds16(src + off + l * 16, ldsrow + off);
            }
        } else {
#pragma unroll
            for (int i = 0; i < 4; ++i) {
                const int off = (wid * 4 + i) * 1024;
                *(f32x4*)(ldsrow + off + l * 16) = (f32x4){0, 0, 0, 0};
            }
        }
    }

    // A fragments (L2-resident) + bias while staging is in flight
    bf16x8 af[9];
    {
        const __bf16* wtp = wt + (size_t)(wid * 16 + lm) * KTOT + lh * 8;
#pragma unroll
        for (int t = 0; t < 9; ++t) af[t] = *(const bf16x8*)(wtp + t * 32);
    }
    float bv[4];
#pragma unroll
    for (int r = 0; r < 4; ++r) bv[r] = bias[wid * 16 + lh * 4 + r];

    __syncthreads();   // drains vmcnt (global_load_lds) + lgkmcnt

    // 9 per-lane swizzled base pointers; swizzle term is nt-independent since
    // (nt*16)>>1 == 0 (mod 4). u<0 (wp=nt*16, u=16nt-1) -> m=3 for all nt>=1;
    // nt=0 case is the all-zero pad so any slot is fine.
    const char* base = (const char*)&xs[0][0][0];
    const char* pr[3][3];
#pragma unroll
    for (int kw = 0; kw < 3; ++kw) {
        const int u = lm + kw - 1;
        const int m = (u < 0) ? 3 : ((u >> 1) & 3);
        const int off = (lm + kw) * 64 + ((lh ^ m) << 4);
#pragma unroll
        for (int kh = 0; kh < 3; ++kh)
            pr[kh][kw] = base + kh * 16512 + off;
    }

    f32x4 acc[16];
#pragma unroll
    for (int nt = 0; nt < 16; ++nt) acc[nt] = (f32x4){0, 0, 0, 0};

#pragma unroll
    for (int nt = 0; nt < 16; ++nt) {
#pragma unroll
        for (int kh = 0; kh < 3; ++kh) {
#pragma unroll
            for (int kw = 0; kw < 3; ++kw) {
                bf16x8 bf = *(const bf16x8*)(pr[kh][kw] + nt * 1024);
                acc[nt] = __builtin_amdgcn_mfma_f32_16x16x32_bf16(af[kh * 3 + kw], bf,
                                                                  acc[nt], 0, 0, 0);
            }
        }
    }

    // D layout: col = l&15 (w), row = (l>>4)*4 + reg (o)
    float* outb = out + (size_t)b * OCH * HH * WW + (size_t)h * WW;
#pragma unroll
    for (int nt = 0; nt < 16; ++nt) {
        const int w0 = nt * 16 + lm;
#pragma unroll
        for (int r2 = 0; r2 < 4; ++r2) {
            const int o = wid * 16 + lh * 4 + r2;
            outb[(size_t)o * HH * WW + w0] = acc[nt][r2] + bv[r2];
        }
    }
}

// ---------------------------------------------------------------------------
// Fallback (round-1 kernel, correct but slower) if workspace is too small.
__global__ __launch_bounds__(256) void conv_fallback_kernel(
        const float* __restrict__ x, const __bf16* __restrict__ wt,
        const float* __restrict__ bias, float* __restrict__ out) {
    const int h = blockIdx.x;
    const int b = blockIdx.y;
    const int tid = threadIdx.x;

    __shared__ __bf16 xs[3][258][CIN];
    {
        const int lane_w = tid & 15;
        const int cp     = tid >> 4;
        const float* xb = x + (size_t)b * CIN * HH * WW;
#pragma unroll
        for (int r = 0; r < 3; ++r) {
            const int row = h - 1 + r;
            const bool rok = (row >= 0) && (row < HH);
#pragma unroll
            for (int j = 0; j < 8; ++j) {
                const int wg0 = j * 32 + lane_w * 2;
                float2 v0 = make_float2(0.f, 0.f), v1 = make_float2(0.f, 0.f);
                if (rok) {
                    const float* p0 = xb + ((size_t)(2 * cp) * HH + row) * WW + wg0;
                    v0 = *(const float2*)p0;
                    v1 = *(const float2*)(p0 + HH * WW);
                }
                bf16x2 pk0 = { (__bf16)v0.x, (__bf16)v1.x };
                bf16x2 pk1 = { (__bf16)v0.y, (__bf16)v1.y };
                *(bf16x2*)&xs[0][0][0 + ((r * 258 + wg0 + 1) * CIN + 2 * cp)] = pk0;
                *(bf16x2*)&xs[0][0][0 + ((r * 258 + wg0 + 2) * CIN + 2 * cp)] = pk1;
            }
        }
        if (tid < 48) {
            int r = tid / 16, cc = (tid % 16) * 2;
            bf16x2 z = { (__bf16)0.f, (__bf16)0.f };
            *(bf16x2*)&xs[r][0][cc]   = z;
            *(bf16x2*)&xs[r][257][cc] = z;
        }
    }
    __syncthreads();

    const int l = tid & 63, wid = tid >> 6;
    const int lm = l & 15, lh = l >> 4;
    bf16x8 af[9];
    {
        const __bf16* wtp = wt + (size_t)(wid * 16 + lm) * KTOT + lh * 8;
#pragma unroll
        for (int t = 0; t < 9; ++t) af[t] = *(const bf16x8*)(wtp + t * 32);
    }
    float bv[4];
#pragma unroll
    for (int r = 0; r < 4; ++r) bv[r] = bias[wid * 16 + lh * 4 + r];

    f32x4 acc[16];
#pragma unroll
    for (int nt = 0; nt < 16; ++nt) acc[nt] = (f32x4){0.f, 0.f, 0.f, 0.f};
#pragma unroll
    for (int nt = 0; nt < 16; ++nt) {
#pragma unroll
        for (int t = 0; t < 9; ++t) {
            const int kh = t / 3, kw = t - kh * 3;
            bf16x8 bf = *(const bf16x8*)&xs[kh][nt * 16 + lm + kw][lh * 8];
            acc[nt] = __builtin_amdgcn_mfma_f32_16x16x32_bf16(af[t], bf, acc[nt], 0, 0, 0);
        }
    }
    float* outb = out + (size_t)b * OCH * HH * WW + (size_t)h * WW;
#pragma unroll
    for (int nt = 0; nt < 16; ++nt) {
        const int w0 = nt * 16 + lm;
#pragma unroll
        for (int r2 = 0; r2 < 4; ++r2) {
            const int o = wid * 16 + lh * 4 + r2;
            outb[(size_t)o * HH * WW + w0] = acc[nt][r2] + bv[r2];
        }
    }
}

// ---------------------------------------------------------------------------
extern "C" void kernel_launch(void* const* d_in, const int* in_sizes, int n_in,
                              void* d_out, int out_size, void* d_ws, size_t ws_size,
                              hipStream_t stream) {
    const float* x    = (const float*)d_in[0];
    const float* w    = (const float*)d_in[1];
    const float* bias = (const float*)d_in[2];
    float* out = (float*)d_out;

    __bf16* wt = (__bf16*)d_ws;                      // 36,864 B at offset 0
    const size_t XT_OFF   = 65536;
    const size_t XT_BYTES = (size_t)16 * HH * WW * CIN * 2;   // 64 MiB
    hipLaunchKernelGGL(wprep_kernel, dim3((OCH * KTOT + 255) / 256), dim3(256), 0,
                       stream, w, wt);

    if (ws_size >= XT_OFF + XT_BYTES) {
        __bf16* xt = (__bf16*)((char*)d_ws + XT_OFF);
        hipLaunchKernelGGL(xprep_kernel, dim3(HH, 16), dim3(256), 0, stream, x, xt);
        hipLaunchKernelGGL(conv_mfma_kernel, dim3(HH * 16), dim3(256), 0, stream,
                           xt, wt, bias, out);
    } else {
        hipLaunchKernelGGL(conv_fallback_kernel, dim3(HH, 16), dim3(256), 0, stream,
                           x, wt, bias, out);
    }
}

// Round 3
// 109.280 us; speedup vs baseline: 1.9566x; 1.2620x over previous
//
#include <hip/hip_runtime.h>
#include <hip/hip_bf16.h>

#define CIN 32
#define OCH 64
#define HH  256
#define WW  256
#define HW  (HH * WW)
#define BH  8                 // output rows per block
#define ROWB (258 * CIN * 2)  // 16512 B per LDS row-slot

typedef __bf16 bf16x8 __attribute__((ext_vector_type(8)));
typedef float  f32x4  __attribute__((ext_vector_type(4)));

// Fused 3x3 conv (implicit GEMM, bf16 MFMA), sliding window over h.
// LDS row-slot layout: w-entry wp (= global w + 1) is 64 B holding 4 chunks of
// 8 channels; chunk for channels sc*8..+7 sits at slot sc ^ ((w>>1)&3).
// Writes: <=2-way bank aliasing (free); ds_read_b128 B-fragments: conflict-free.
__global__ __launch_bounds__(256, 2) void conv_fused_kernel(
        const float* __restrict__ x, const float* __restrict__ wgt,
        const float* __restrict__ bias, float* __restrict__ out) {
    // chunked XCD swizzle: each XCD gets 64 consecutive nids = 2 full batches,
    // so h-adjacent tiles (sharing 2 halo rows) run on the same XCD's L2.
    const int bid = blockIdx.x;                  // 512 blocks
    const int nid = (bid & 7) * 64 + (bid >> 3);
    const int b   = nid >> 5;                    // 0..15
    const int h0  = (nid & 31) * BH;             // 0..248
    const int tid = threadIdx.x;
    const int l   = tid & 63, wid = tid >> 6;    // wave id = channel-group / o-group
    const int lm  = l & 15,  lh  = l >> 4;

    __shared__ __bf16 xs[4][258][CIN];           // 66,048 B ring of 4 row-slots
    char* lds = (char*)&xs[0][0][0];
    const float* xb = x + (size_t)b * CIN * HW;

    // zero the w-pad entries (wp=0 and wp=257) of all 4 slots
    if (tid < 32) {
        const int s = tid >> 3, k = tid & 7;
        const int wp = (k < 4) ? 0 : 257;
        *(f32x4*)(lds + s * ROWB + wp * 64 + (k & 3) * 16) = (f32x4){0, 0, 0, 0};
    }

    // ---- weights inline (L2-hot): af[t][j] = w[o][(lh*8+j)*9 + t], o=wid*16+lm
    bf16x8 af[9];
    {
        const float* wp_ = wgt + (size_t)(wid * 16 + lm) * 288 + (size_t)lh * 8 * 9;
#pragma unroll
        for (int t = 0; t < 9; ++t)
#pragma unroll
            for (int j = 0; j < 8; ++j)
                af[t][j] = (__bf16)wp_[j * 9 + t];
    }
    float bv[4];
#pragma unroll
    for (int r = 0; r < 4; ++r) bv[r] = bias[wid * 16 + lh * 4 + r];

    // ---- full staging of one row (prologue use)
    auto stage = [&](int row) {
        char* slot = lds + ((row + 1) & 3) * ROWB;
        if (row >= 0 && row < HH) {
            const float* rp = xb + (size_t)row * WW;
#pragma unroll
            for (int wh = 0; wh < 2; ++wh) {
                float2 v[8];
#pragma unroll
                for (int j = 0; j < 8; ++j)
                    v[j] = *(const float2*)(rp + (size_t)(wid * 8 + j) * HW + wh * 128 + 2 * l);
#pragma unroll
                for (int p = 0; p < 2; ++p) {
                    const int w = wh * 128 + 2 * l + p;
                    bf16x8 pk;
#pragma unroll
                    for (int j = 0; j < 8; ++j) pk[j] = (__bf16)(p ? v[j].y : v[j].x);
                    *(bf16x8*)(slot + (w + 1) * 64 + ((wid ^ ((w >> 1) & 3)) << 4)) = pk;
                }
            }
        } else {
#pragma unroll
            for (int wh = 0; wh < 2; ++wh)
#pragma unroll
                for (int p = 0; p < 2; ++p) {
                    const int w = wh * 128 + 2 * l + p;
                    *(f32x4*)(slot + (w + 1) * 64 + ((wid ^ ((w >> 1) & 3)) << 4)) =
                        (f32x4){0, 0, 0, 0};
                }
        }
    };

    stage(h0 - 1); stage(h0); stage(h0 + 1);

    // per-lane swizzled w-entry offsets for the 3 kw taps (nt-independent)
    int off[3];
#pragma unroll
    for (int kw = 0; kw < 3; ++kw) {
        const int u = lm + kw - 1;                   // global w of the entry
        const int m = (u < 0) ? 3 : ((u >> 1) & 3);  // u<0 is the zero pad
        off[kw] = (lm + kw) * 64 + ((lh ^ m) << 4);
    }

    __syncthreads();

    for (int i = 0; i < BH; ++i) {
        const int h  = h0 + i;
        const int nr = h + 2;                          // row to prefetch
        const bool ldnext = (i < BH - 1) && (nr < HH);
        const bool zrnext = (i < BH - 1) && (nr >= HH);

        // T14 issue-early: global loads for row h+2 (consumed after compute)
        float2 v[16];
        if (ldnext) {
            const float* rp = xb + (size_t)nr * WW;
#pragma unroll
            for (int wh = 0; wh < 2; ++wh)
#pragma unroll
                for (int j = 0; j < 8; ++j)
                    v[wh * 8 + j] =
                        *(const float2*)(rp + (size_t)(wid * 8 + j) * HW + wh * 128 + 2 * l);
        }

        // ---- compute output row h from slots (h)&3,(h+1)&3,(h+2)&3
        const char* base[3] = { lds + ((h    ) & 3) * ROWB,
                                lds + ((h + 1) & 3) * ROWB,
                                lds + ((h + 2) & 3) * ROWB };
        f32x4 acc[16];
#pragma unroll
        for (int nt = 0; nt < 16; ++nt) acc[nt] = (f32x4){0, 0, 0, 0};
#pragma unroll
        for (int nt = 0; nt < 16; ++nt)
#pragma unroll
            for (int kh = 0; kh < 3; ++kh)
#pragma unroll
                for (int kw = 0; kw < 3; ++kw) {
                    bf16x8 bf = *(const bf16x8*)(base[kh] + off[kw] + nt * 1024);
                    acc[nt] = __builtin_amdgcn_mfma_f32_16x16x32_bf16(
                        af[kh * 3 + kw], bf, acc[nt], 0, 0, 0);
                }

        // ---- store row h (D: col=l&15 -> w, row=(l>>4)*4+reg -> o)
        float* outb = out + (size_t)b * OCH * HW + (size_t)h * WW;
#pragma unroll
        for (int nt = 0; nt < 16; ++nt)
#pragma unroll
            for (int r2 = 0; r2 < 4; ++r2)
                outb[(size_t)(wid * 16 + lh * 4 + r2) * HW + nt * 16 + lm] =
                    acc[nt][r2] + bv[r2];

        // ---- write-late: cvt + ds_write row h+2 into slot (h+3)&3
        // (disjoint from the 3 slots read above; prior reader separated by the
        //  barrier at the end of the previous iteration)
        if (ldnext) {
            char* slot = lds + ((nr + 1) & 3) * ROWB;
#pragma unroll
            for (int wh = 0; wh < 2; ++wh)
#pragma unroll
                for (int p = 0; p < 2; ++p) {
                    const int w = wh * 128 + 2 * l + p;
                    bf16x8 pk;
#pragma unroll
                    for (int j = 0; j < 8; ++j)
                        pk[j] = (__bf16)(p ? v[wh * 8 + j].y : v[wh * 8 + j].x);
                    *(bf16x8*)(slot + (w + 1) * 64 + ((wid ^ ((w >> 1) & 3)) << 4)) = pk;
                }
        } else if (zrnext) {
            char* slot = lds + ((nr + 1) & 3) * ROWB;
#pragma unroll
            for (int wh = 0; wh < 2; ++wh)
#pragma unroll
                for (int p = 0; p < 2; ++p) {
                    const int w = wh * 128 + 2 * l + p;
                    *(f32x4*)(slot + (w + 1) * 64 + ((wid ^ ((w >> 1) & 3)) << 4)) =
                        (f32x4){0, 0, 0, 0};
                }
        }
        __syncthreads();
    }
}

extern "C" void kernel_launch(void* const* d_in, const int* in_sizes, int n_in,
                              void* d_out, int out_size, void* d_ws, size_t ws_size,
                              hipStream_t stream) {
    const float* x    = (const float*)d_in[0];
    const float* w    = (const float*)d_in[1];
    const float* bias = (const float*)d_in[2];
    float* out = (float*)d_out;

    hipLaunchKernelGGL(conv_fused_kernel, dim3(16 * (HH / BH)), dim3(256), 0, stream,
                       x, w, bias, out);
}